// Round 1
// baseline (677.483 us; speedup 1.0000x reference)
//
#include <hip/hip_runtime.h>

#define B_   16
#define T_   2048
#define D_   1024
#define TT_  2046
#define W_   682            // MAX_WORDS
#define BW_  (B_ * W_)      // 10912
#define NMUT 64
#define NBIN 32

// ---------------------------------------------------------------------------
// K1: word boundaries via block scan. One block per batch row.
// starts[b][w] = first token index of word w; starts[b][nw] = TT_.
// ---------------------------------------------------------------------------
__global__ __launch_bounds__(256) void k_bounds(const int* __restrict__ ws,
                                                int* __restrict__ starts,
                                                int* __restrict__ nwords) {
    int b   = blockIdx.x;
    int tid = threadIdx.x;
    const int* row = ws + (size_t)b * TT_;

    int vals[8], incl[8];
    int p = 0;
    int t0 = tid * 8;
#pragma unroll
    for (int i = 0; i < 8; ++i) {
        int t = t0 + i;
        int v = (t < TT_) ? row[t] : 0;
        vals[i] = v;
        p += v;
        incl[i] = p;
    }
    int tot = p;

    // wave-64 inclusive scan of per-thread totals
    int lane = tid & 63;
    int x = tot;
#pragma unroll
    for (int off = 1; off < 64; off <<= 1) {
        int v = __shfl_up(x, off);
        if (lane >= off) x += v;
    }

    __shared__ int wsum[4];
    int wid = tid >> 6;
    if (lane == 63) wsum[wid] = x;
    __syncthreads();

    int wbase = 0;
    for (int w = 0; w < wid; ++w) wbase += wsum[w];
    int excl = wbase + x - tot;   // exclusive prefix for this thread

    int* st = starts + (size_t)b * (W_ + 1);
#pragma unroll
    for (int i = 0; i < 8; ++i) {
        if (vals[i]) {
            int w = excl + incl[i] - 1;
            if (w <= W_) st[w] = t0 + i;
        }
    }
    if (tid == 0) {
        int total = wsum[0] + wsum[1] + wsum[2] + wsum[3];
        int nw = total < W_ ? total : W_;
        nwords[b] = nw;
        if (total <= W_) st[total] = TT_;
    }
}

// ---------------------------------------------------------------------------
// K2: word feature sums. One block per (b, w); 256 threads x float4 = 1024 f32.
// ---------------------------------------------------------------------------
__global__ __launch_bounds__(256) void k_wf(const float* __restrict__ feat,
                                            const int* __restrict__ starts,
                                            const int* __restrict__ nwords,
                                            float* __restrict__ wf) {
    int blk = blockIdx.x;
    int b = blk / W_;
    int w = blk - b * W_;
    int tid = threadIdx.x;
    float4* outp = (float4*)(wf + (size_t)blk * D_) + tid;
    int nw = nwords[b];
    if (w >= nw) {                       // empty segment -> ones (reference)
        *outp = make_float4(1.f, 1.f, 1.f, 1.f);
        return;
    }
    const int* st = starts + (size_t)b * (W_ + 1);
    int s = st[w], e = st[w + 1];
    const float4* base = (const float4*)(feat + ((size_t)b * T_ + 1) * D_) + tid;
    float4 acc = make_float4(0.f, 0.f, 0.f, 0.f);
    for (int t = s; t < e; ++t) {
        float4 v = base[(size_t)t * (D_ / 4)];
        acc.x += v.x; acc.y += v.y; acc.z += v.z; acc.w += v.w;
    }
    *outp = acc;
}

// ---------------------------------------------------------------------------
// K3: fold bin_w's wcl-columns through out_w:
//   W_eff[j][k] = bin_w[j][64+k] + sum_c bin_w[j][c] * out_w[c][k]
//   b_eff[j]    = bin_b[j]       + sum_c bin_w[j][c] * out_b[c]
// ---------------------------------------------------------------------------
__global__ __launch_bounds__(256) void k_weff(const float* __restrict__ bin_w,
                                              const float* __restrict__ bin_b,
                                              const float* __restrict__ out_w,
                                              const float* __restrict__ out_b,
                                              float* __restrict__ weff,
                                              float* __restrict__ beff) {
    __shared__ float bc[NMUT];
    int j = blockIdx.x, tid = threadIdx.x;
    if (tid < NMUT) bc[tid] = bin_w[(size_t)j * (D_ + NMUT) + tid];
    __syncthreads();
    for (int k = tid; k < D_; k += 256) {
        float acc = bin_w[(size_t)j * (D_ + NMUT) + NMUT + k];
#pragma unroll 8
        for (int c = 0; c < NMUT; ++c)
            acc = fmaf(bc[c], out_w[(size_t)c * D_ + k], acc);
        weff[(size_t)j * D_ + k] = acc;
    }
    if (tid == 0) {
        float acc = bin_b[j];
        for (int c = 0; c < NMUT; ++c) acc = fmaf(bc[c], out_b[c], acc);
        beff[j] = acc;
    }
}

// ---------------------------------------------------------------------------
// K4: h = tanh(wf . dense_w^T + dense_b).  M=10912, N=K=1024, NT layout.
// 64x64 tile, BK=32, transposed LDS ([k][m]) so compute reads are b128.
// ---------------------------------------------------------------------------
__global__ __launch_bounds__(256) void k_gemm1(const float* __restrict__ wf,
                                               const float* __restrict__ dw,
                                               const float* __restrict__ db,
                                               float* __restrict__ h) {
    __shared__ float As[32 * 64];
    __shared__ float Bs[32 * 64];
    int tid = threadIdx.x;
    int bm = blockIdx.x * 64;
    int bn = blockIdx.y * 64;
    int tx = tid & 15, ty = tid >> 4;
    float acc[4][4] = {{0.f}};

    int lrow = tid >> 3;          // 0..31
    int lk4  = (tid & 7) << 2;    // 0,4,...,28

    for (int kt = 0; kt < D_; kt += 32) {
#pragma unroll
        for (int half = 0; half < 2; ++half) {
            int r  = lrow + half * 32;
            int gm = bm + r;
            float4 av = make_float4(0.f, 0.f, 0.f, 0.f);
            if (gm < BW_) av = *(const float4*)(wf + (size_t)gm * D_ + kt + lk4);
            As[(lk4 + 0) * 64 + r] = av.x;
            As[(lk4 + 1) * 64 + r] = av.y;
            As[(lk4 + 2) * 64 + r] = av.z;
            As[(lk4 + 3) * 64 + r] = av.w;
            float4 bv = *(const float4*)(dw + (size_t)(bn + r) * D_ + kt + lk4);
            Bs[(lk4 + 0) * 64 + r] = bv.x;
            Bs[(lk4 + 1) * 64 + r] = bv.y;
            Bs[(lk4 + 2) * 64 + r] = bv.z;
            Bs[(lk4 + 3) * 64 + r] = bv.w;
        }
        __syncthreads();
#pragma unroll
        for (int kk = 0; kk < 32; ++kk) {
            float4 a = *(const float4*)&As[kk * 64 + (ty << 2)];
            float4 b = *(const float4*)&Bs[kk * 64 + (tx << 2)];
            acc[0][0] = fmaf(a.x, b.x, acc[0][0]);
            acc[0][1] = fmaf(a.x, b.y, acc[0][1]);
            acc[0][2] = fmaf(a.x, b.z, acc[0][2]);
            acc[0][3] = fmaf(a.x, b.w, acc[0][3]);
            acc[1][0] = fmaf(a.y, b.x, acc[1][0]);
            acc[1][1] = fmaf(a.y, b.y, acc[1][1]);
            acc[1][2] = fmaf(a.y, b.z, acc[1][2]);
            acc[1][3] = fmaf(a.y, b.w, acc[1][3]);
            acc[2][0] = fmaf(a.z, b.x, acc[2][0]);
            acc[2][1] = fmaf(a.z, b.y, acc[2][1]);
            acc[2][2] = fmaf(a.z, b.z, acc[2][2]);
            acc[2][3] = fmaf(a.z, b.w, acc[2][3]);
            acc[3][0] = fmaf(a.w, b.x, acc[3][0]);
            acc[3][1] = fmaf(a.w, b.y, acc[3][1]);
            acc[3][2] = fmaf(a.w, b.z, acc[3][2]);
            acc[3][3] = fmaf(a.w, b.w, acc[3][3]);
        }
        __syncthreads();
    }

    float4 bias = *(const float4*)(db + bn + (tx << 2));
#pragma unroll
    for (int i = 0; i < 4; ++i) {
        int gm = bm + (ty << 2) + i;
        if (gm < BW_) {
            float4 o;
            o.x = tanhf(acc[i][0] + bias.x);
            o.y = tanhf(acc[i][1] + bias.y);
            o.z = tanhf(acc[i][2] + bias.z);
            o.w = tanhf(acc[i][3] + bias.w);
            *(float4*)(h + (size_t)gm * D_ + bn + (tx << 2)) = o;
        }
    }
}

// ---------------------------------------------------------------------------
// K5: [wcl | bin] = h . [out_w | W_eff]^T + [out_b | b_eff].  N = 96, K=1024.
// 64-row tile; thread (tx 0..31, ty 0..7) computes 8 rows x 3 cols.
// ---------------------------------------------------------------------------
__global__ __launch_bounds__(256) void k_gemm2(const float* __restrict__ h,
                                               const float* __restrict__ out_w,
                                               const float* __restrict__ out_b,
                                               const float* __restrict__ weff,
                                               const float* __restrict__ beff,
                                               float* __restrict__ out) {
    __shared__ float As[32 * 64];     // [k][m]
    __shared__ float Bs[96 * 33];     // [n][k] padded
    int tid = threadIdx.x;
    int bm = blockIdx.x * 64;
    int tx = tid & 31;
    int ty = tid >> 5;                // 0..7
    float acc[8][3] = {{0.f}};

    int lrow = tid >> 3;
    int lk4  = (tid & 7) << 2;

    for (int kt = 0; kt < D_; kt += 32) {
#pragma unroll
        for (int half = 0; half < 2; ++half) {
            int r  = lrow + half * 32;
            int gm = bm + r;
            float4 av = make_float4(0.f, 0.f, 0.f, 0.f);
            if (gm < BW_) av = *(const float4*)(h + (size_t)gm * D_ + kt + lk4);
            As[(lk4 + 0) * 64 + r] = av.x;
            As[(lk4 + 1) * 64 + r] = av.y;
            As[(lk4 + 2) * 64 + r] = av.z;
            As[(lk4 + 3) * 64 + r] = av.w;
        }
#pragma unroll
        for (int q = 0; q < 3; ++q) {
            int idx = tid + q * 256;
            int n   = idx >> 3;            // 0..95
            int k4  = (idx & 7) << 2;
            const float* src = (n < NMUT) ? (out_w + (size_t)n * D_)
                                          : (weff + (size_t)(n - NMUT) * D_);
            float4 bv = *(const float4*)(src + kt + k4);
            Bs[n * 33 + k4 + 0] = bv.x;
            Bs[n * 33 + k4 + 1] = bv.y;
            Bs[n * 33 + k4 + 2] = bv.z;
            Bs[n * 33 + k4 + 3] = bv.w;
        }
        __syncthreads();
#pragma unroll
        for (int kk = 0; kk < 32; ++kk) {
            float4 al = *(const float4*)&As[kk * 64 + (ty << 3)];
            float4 ah = *(const float4*)&As[kk * 64 + (ty << 3) + 4];
            float b0 = Bs[tx * 33 + kk];
            float b1 = Bs[(32 + tx) * 33 + kk];
            float b2 = Bs[(64 + tx) * 33 + kk];
            acc[0][0] = fmaf(al.x, b0, acc[0][0]);
            acc[0][1] = fmaf(al.x, b1, acc[0][1]);
            acc[0][2] = fmaf(al.x, b2, acc[0][2]);
            acc[1][0] = fmaf(al.y, b0, acc[1][0]);
            acc[1][1] = fmaf(al.y, b1, acc[1][1]);
            acc[1][2] = fmaf(al.y, b2, acc[1][2]);
            acc[2][0] = fmaf(al.z, b0, acc[2][0]);
            acc[2][1] = fmaf(al.z, b1, acc[2][1]);
            acc[2][2] = fmaf(al.z, b2, acc[2][2]);
            acc[3][0] = fmaf(al.w, b0, acc[3][0]);
            acc[3][1] = fmaf(al.w, b1, acc[3][1]);
            acc[3][2] = fmaf(al.w, b2, acc[3][2]);
            acc[4][0] = fmaf(ah.x, b0, acc[4][0]);
            acc[4][1] = fmaf(ah.x, b1, acc[4][1]);
            acc[4][2] = fmaf(ah.x, b2, acc[4][2]);
            acc[5][0] = fmaf(ah.y, b0, acc[5][0]);
            acc[5][1] = fmaf(ah.y, b1, acc[5][1]);
            acc[5][2] = fmaf(ah.y, b2, acc[5][2]);
            acc[6][0] = fmaf(ah.z, b0, acc[6][0]);
            acc[6][1] = fmaf(ah.z, b1, acc[6][1]);
            acc[6][2] = fmaf(ah.z, b2, acc[6][2]);
            acc[7][0] = fmaf(ah.w, b0, acc[7][0]);
            acc[7][1] = fmaf(ah.w, b1, acc[7][1]);
            acc[7][2] = fmaf(ah.w, b2, acc[7][2]);
        }
        __syncthreads();
    }

    float bo0 = out_b[tx];
    float bo1 = out_b[32 + tx];
    float bo2 = beff[tx];
#pragma unroll
    for (int i = 0; i < 8; ++i) {
        int gm = bm + (ty << 3) + i;
        if (gm < BW_) {
            out[(size_t)gm * NMUT + tx]        = acc[i][0] + bo0;
            out[(size_t)gm * NMUT + 32 + tx]   = acc[i][1] + bo1;
            out[(size_t)BW_ * NMUT + (size_t)gm * NBIN + tx] = acc[i][2] + bo2;
        }
    }
}

// ---------------------------------------------------------------------------
extern "C" void kernel_launch(void* const* d_in, const int* in_sizes, int n_in,
                              void* d_out, int out_size, void* d_ws, size_t ws_size,
                              hipStream_t stream) {
    const float* feat    = (const float*)d_in[0];
    const int*   wstarts = (const int*)d_in[1];
    const float* dw      = (const float*)d_in[2];
    const float* db      = (const float*)d_in[3];
    const float* ow      = (const float*)d_in[4];
    const float* ob      = (const float*)d_in[5];
    const float* bw      = (const float*)d_in[6];
    const float* bb      = (const float*)d_in[7];
    float* out = (float*)d_out;

    char* ws = (char*)d_ws;
    float* wf   = (float*)ws;                                   // BW_*D_ f32
    float* h    = (float*)(ws + (size_t)BW_ * D_ * 4);          // BW_*D_ f32
    float* weff = (float*)(ws + (size_t)BW_ * D_ * 8);          // 32*1024 f32
    float* beff = weff + (size_t)NBIN * D_;                     // 32 f32
    int* starts = (int*)(beff + NBIN);                          // B_*(W_+1)
    int* nwords = starts + (size_t)B_ * (W_ + 1);               // B_

    k_bounds<<<B_, 256, 0, stream>>>(wstarts, starts, nwords);
    k_weff<<<NBIN, 256, 0, stream>>>(bw, bb, ow, ob, weff, beff);
    k_wf<<<BW_, 256, 0, stream>>>(feat, starts, nwords, wf);
    k_gemm1<<<dim3((BW_ + 63) / 64, D_ / 64), 256, 0, stream>>>(wf, dw, db, h);
    k_gemm2<<<(BW_ + 63) / 64, 256, 0, stream>>>(h, ow, ob, weff, beff, out);
}

// Round 2
// 301.578 us; speedup vs baseline: 2.2465x; 2.2465x over previous
//
#include <hip/hip_runtime.h>
#include <stdint.h>

#define B_   16
#define T_   2048
#define D_   1024
#define TT_  2046
#define W_   682            // MAX_WORDS
#define BW_  (B_ * W_)      // 10912
#define NMUT 64
#define NBIN 32

typedef __attribute__((ext_vector_type(8))) short s8b;    // 8 bf16 (4 VGPRs)
typedef __attribute__((ext_vector_type(4))) float f32x4;

__device__ inline short f2bf(float f) {                   // RNE f32->bf16
    uint32_t u = __builtin_bit_cast(uint32_t, f);
    u += 0x7FFFu + ((u >> 16) & 1u);
    return (short)(u >> 16);
}

__device__ inline void gload_lds16(const void* g, void* l) {
    __builtin_amdgcn_global_load_lds(
        (const __attribute__((address_space(1))) uint32_t*)g,
        (__attribute__((address_space(3))) uint32_t*)l, 16, 0, 0);
}

// ---------------------------------------------------------------------------
// K1: word boundaries via block scan. One block per batch row.
// ---------------------------------------------------------------------------
__global__ __launch_bounds__(256) void k_bounds(const int* __restrict__ ws,
                                                int* __restrict__ starts,
                                                int* __restrict__ nwords) {
    int b   = blockIdx.x;
    int tid = threadIdx.x;
    const int* row = ws + (size_t)b * TT_;

    int vals[8], incl[8];
    int p = 0;
    int t0 = tid * 8;
#pragma unroll
    for (int i = 0; i < 8; ++i) {
        int t = t0 + i;
        int v = (t < TT_) ? row[t] : 0;
        vals[i] = v;
        p += v;
        incl[i] = p;
    }
    int tot = p;

    int lane = tid & 63;
    int x = tot;
#pragma unroll
    for (int off = 1; off < 64; off <<= 1) {
        int v = __shfl_up(x, off);
        if (lane >= off) x += v;
    }

    __shared__ int wsum[4];
    int wid = tid >> 6;
    if (lane == 63) wsum[wid] = x;
    __syncthreads();

    int wbase = 0;
    for (int w = 0; w < wid; ++w) wbase += wsum[w];
    int excl = wbase + x - tot;

    int* st = starts + (size_t)b * (W_ + 1);
#pragma unroll
    for (int i = 0; i < 8; ++i) {
        if (vals[i]) {
            int w = excl + incl[i] - 1;
            if (w <= W_) st[w] = t0 + i;
        }
    }
    if (tid == 0) {
        int total = wsum[0] + wsum[1] + wsum[2] + wsum[3];
        int nw = total < W_ ? total : W_;
        nwords[b] = nw;
        if (total <= W_) st[total] = TT_;
    }
}

// ---------------------------------------------------------------------------
// K2: word feature sums -> bf16. One block per (b, w).
// ---------------------------------------------------------------------------
__global__ __launch_bounds__(256) void k_wf(const float* __restrict__ feat,
                                            const int* __restrict__ starts,
                                            const int* __restrict__ nwords,
                                            short* __restrict__ wf) {
    int blk = blockIdx.x;
    int b = blk / W_;
    int w = blk - b * W_;
    int tid = threadIdx.x;
    short* outp = wf + (size_t)blk * D_ + tid * 4;
    int nw = nwords[b];
    float4 acc = make_float4(0.f, 0.f, 0.f, 0.f);
    if (w >= nw) {
        acc = make_float4(1.f, 1.f, 1.f, 1.f);
    } else {
        const int* st = starts + (size_t)b * (W_ + 1);
        int s = st[w], e = st[w + 1];
        const float4* base = (const float4*)(feat + ((size_t)b * T_ + 1) * D_) + tid;
        for (int t = s; t < e; ++t) {
            float4 v = base[(size_t)t * (D_ / 4)];
            acc.x += v.x; acc.y += v.y; acc.z += v.z; acc.w += v.w;
        }
    }
    short4 o;
    o.x = f2bf(acc.x); o.y = f2bf(acc.y); o.z = f2bf(acc.z); o.w = f2bf(acc.w);
    *(short4*)outp = o;
}

// ---------------------------------------------------------------------------
// K3a: fp32 -> bf16 cast (dense_w, out_w)
// ---------------------------------------------------------------------------
__global__ __launch_bounds__(256) void k_cvt(const float* __restrict__ src,
                                             short* __restrict__ dst, int n4) {
    int i = blockIdx.x * 256 + threadIdx.x;
    if (i < n4) {
        float4 v = ((const float4*)src)[i];
        short4 o;
        o.x = f2bf(v.x); o.y = f2bf(v.y); o.z = f2bf(v.z); o.w = f2bf(v.w);
        *(short4*)(dst + (size_t)i * 4) = o;
    }
}

// ---------------------------------------------------------------------------
// K3b: fold bin_w's wcl-columns through out_w; write bf16 rows 64..95 of Bcat.
//   W_eff[j][k] = bin_w[j][64+k] + sum_c bin_w[j][c] * out_w[c][k]
//   b_eff[j]    = bin_b[j]       + sum_c bin_w[j][c] * out_b[c]
// ---------------------------------------------------------------------------
__global__ __launch_bounds__(256) void k_weff(const float* __restrict__ bin_w,
                                              const float* __restrict__ bin_b,
                                              const float* __restrict__ out_w,
                                              const float* __restrict__ out_b,
                                              short* __restrict__ Bcat,
                                              float* __restrict__ beff) {
    __shared__ float bc[NMUT];
    int j = blockIdx.x, tid = threadIdx.x;
    if (tid < NMUT) bc[tid] = bin_w[(size_t)j * (D_ + NMUT) + tid];
    __syncthreads();
    for (int k = tid; k < D_; k += 256) {
        float acc = bin_w[(size_t)j * (D_ + NMUT) + NMUT + k];
#pragma unroll 8
        for (int c = 0; c < NMUT; ++c)
            acc = fmaf(bc[c], out_w[(size_t)c * D_ + k], acc);
        Bcat[(size_t)(NMUT + j) * D_ + k] = f2bf(acc);
    }
    if (tid == 0) {
        float acc = bin_b[j];
        for (int c = 0; c < NMUT; ++c) acc = fmaf(bc[c], out_b[c], acc);
        beff[j] = acc;
    }
}

// ---------------------------------------------------------------------------
// K4: h = tanh(wf . dense_w^T + db)  via MFMA bf16. m97 recipe:
// 128x128 tile, BK=32, global_load_lds width-16, 4 waves of 64x64.
// C/D layout: col = lane&15, row = (lane>>4)*4 + reg   [m89-verified]
// ---------------------------------------------------------------------------
__global__ __launch_bounds__(256) void k_gemm1(const short* __restrict__ wf,
                                               const short* __restrict__ dwb,
                                               const float* __restrict__ db,
                                               short* __restrict__ h) {
    __shared__ short As[128 * 32];
    __shared__ short Bs[128 * 32];
    int tid  = threadIdx.x;
    int lane = tid & 63;
    int w    = tid >> 6;
    int wm = w >> 1, wn = w & 1;
    int bm = blockIdx.x * 128;
    int bn = blockIdx.y * 128;

    int ln = lane & 15;          // n/m index within 16
    int qk = lane >> 4;          // quad -> k-chunk (frag) / row-group (C)

    int srow = lane >> 2;        // staging: 16 rows per 1KB chunk
    int scol = (lane & 3) * 8;   // 4 x 8 bf16 = 32 k per row

    f32x4 acc[4][4];
#pragma unroll
    for (int i = 0; i < 4; ++i)
#pragma unroll
        for (int j = 0; j < 4; ++j) acc[i][j] = (f32x4){0.f, 0.f, 0.f, 0.f};

    for (int kt = 0; kt < D_; kt += 32) {
#pragma unroll
        for (int p = 0; p < 2; ++p) {
            int chunk = w * 2 + p;               // 0..7, 16 rows each
            int arow = bm + chunk * 16 + srow;
            arow = arow < BW_ ? arow : BW_ - 1;  // clamp tail (stores masked)
            gload_lds16(wf + (size_t)arow * D_ + kt + scol, &As[chunk * 512]);
            int brow = bn + chunk * 16 + srow;   // always < 1024
            gload_lds16(dwb + (size_t)brow * D_ + kt + scol, &Bs[chunk * 512]);
        }
        __syncthreads();
        s8b af[4], bf[4];
#pragma unroll
        for (int i = 0; i < 4; ++i)
            af[i] = *(const s8b*)&As[(wm * 64 + i * 16 + ln) * 32 + qk * 8];
#pragma unroll
        for (int j = 0; j < 4; ++j)
            bf[j] = *(const s8b*)&Bs[(wn * 64 + j * 16 + ln) * 32 + qk * 8];
#pragma unroll
        for (int i = 0; i < 4; ++i)
#pragma unroll
            for (int j = 0; j < 4; ++j)
                acc[i][j] = __builtin_amdgcn_mfma_f32_16x16x32_bf16(
                    af[i], bf[j], acc[i][j], 0, 0, 0);
        __syncthreads();
    }

    float bias[4];
#pragma unroll
    for (int j = 0; j < 4; ++j) bias[j] = db[bn + wn * 64 + j * 16 + ln];
#pragma unroll
    for (int i = 0; i < 4; ++i) {
        int row0 = bm + wm * 64 + i * 16 + qk * 4;
#pragma unroll
        for (int r = 0; r < 4; ++r) {
            int row = row0 + r;
            if (row < BW_) {
#pragma unroll
                for (int j = 0; j < 4; ++j) {
                    int cn = bn + wn * 64 + j * 16 + ln;
                    h[(size_t)row * D_ + cn] = f2bf(tanhf(acc[i][j][r] + bias[j]));
                }
            }
        }
    }
}

// ---------------------------------------------------------------------------
// K5: [wcl | bin] = h . Bcat^T + bias via MFMA. M-tile 64, N=96 (6 frags).
// A staged via global_load_lds; B frags direct from global (L2-hot 192KB),
// software-pipelined one K-step ahead.
// ---------------------------------------------------------------------------
__global__ __launch_bounds__(256) void k_gemm2(const short* __restrict__ h,
                                               const short* __restrict__ Bcat,
                                               const float* __restrict__ ob,
                                               const float* __restrict__ beff,
                                               float* __restrict__ out) {
    __shared__ short As[64 * 32];
    int tid  = threadIdx.x;
    int lane = tid & 63;
    int w    = tid >> 6;           // wave -> 16-row band
    int ln = lane & 15, qk = lane >> 4;
    int m0 = blockIdx.x * 64;
    int srow = lane >> 2, scol = (lane & 3) * 8;

    f32x4 acc[6];
#pragma unroll
    for (int j = 0; j < 6; ++j) acc[j] = (f32x4){0.f, 0.f, 0.f, 0.f};

    s8b bcur[6];
#pragma unroll
    for (int j = 0; j < 6; ++j)
        bcur[j] = *(const s8b*)(Bcat + (size_t)(j * 16 + ln) * D_ + qk * 8);

    for (int kt = 0; kt < D_; kt += 32) {
        int arow = m0 + w * 16 + srow;
        arow = arow < BW_ ? arow : BW_ - 1;
        gload_lds16(h + (size_t)arow * D_ + kt + scol, &As[w * 512]);
        __syncthreads();
        s8b af = *(const s8b*)&As[(w * 16 + ln) * 32 + qk * 8];
        int ktn = (kt + 32 < D_) ? kt + 32 : 0;
        s8b bnext[6];
#pragma unroll
        for (int j = 0; j < 6; ++j)
            bnext[j] = *(const s8b*)(Bcat + (size_t)(j * 16 + ln) * D_ + ktn + qk * 8);
#pragma unroll
        for (int j = 0; j < 6; ++j)
            acc[j] = __builtin_amdgcn_mfma_f32_16x16x32_bf16(af, bcur[j], acc[j], 0, 0, 0);
        __syncthreads();
#pragma unroll
        for (int j = 0; j < 6; ++j) bcur[j] = bnext[j];
    }

    float bj[6];
#pragma unroll
    for (int j = 0; j < 6; ++j) {
        int c = j * 16 + ln;
        bj[j] = (c < NMUT) ? ob[c] : beff[c - NMUT];
    }
#pragma unroll
    for (int r = 0; r < 4; ++r) {
        int row = m0 + w * 16 + qk * 4 + r;
        if (row < BW_) {
#pragma unroll
            for (int j = 0; j < 6; ++j) {
                int c = j * 16 + ln;
                float v = acc[j][r] + bj[j];
                if (c < NMUT) out[(size_t)row * NMUT + c] = v;
                else out[(size_t)BW_ * NMUT + (size_t)row * NBIN + (c - NMUT)] = v;
            }
        }
    }
}

// ---------------------------------------------------------------------------
extern "C" void kernel_launch(void* const* d_in, const int* in_sizes, int n_in,
                              void* d_out, int out_size, void* d_ws, size_t ws_size,
                              hipStream_t stream) {
    const float* feat    = (const float*)d_in[0];
    const int*   wstarts = (const int*)d_in[1];
    const float* dw      = (const float*)d_in[2];
    const float* db      = (const float*)d_in[3];
    const float* ow      = (const float*)d_in[4];
    const float* ob      = (const float*)d_in[5];
    const float* bw      = (const float*)d_in[6];
    const float* bb      = (const float*)d_in[7];
    float* out = (float*)d_out;

    char* ws = (char*)d_ws;
    size_t off = 0;
    auto alloc = [&](size_t bytes) {
        void* p = ws + off;
        off += (bytes + 255) & ~(size_t)255;
        return p;
    };
    short* wf     = (short*)alloc((size_t)BW_ * D_ * 2);
    short* h      = (short*)alloc((size_t)BW_ * D_ * 2);
    short* dwb    = (short*)alloc((size_t)D_ * D_ * 2);
    short* Bcat   = (short*)alloc((size_t)(NMUT + NBIN) * D_ * 2);
    float* beff   = (float*)alloc(NBIN * 4);
    int*   starts = (int*)alloc((size_t)B_ * (W_ + 1) * 4);
    int*   nwords = (int*)alloc(B_ * 4);

    k_bounds<<<B_, 256, 0, stream>>>(wstarts, starts, nwords);
    k_cvt<<<(D_ * D_ / 4 + 255) / 256, 256, 0, stream>>>(dw, dwb, D_ * D_ / 4);
    k_cvt<<<(NMUT * D_ / 4 + 255) / 256, 256, 0, stream>>>(ow, Bcat, NMUT * D_ / 4);
    k_weff<<<NBIN, 256, 0, stream>>>(bw, bb, ow, ob, Bcat, beff);
    k_wf<<<BW_, 256, 0, stream>>>(feat, starts, nwords, wf);
    k_gemm1<<<dim3((BW_ + 127) / 128, D_ / 128), 256, 0, stream>>>(wf, dwb, db, h);
    k_gemm2<<<(BW_ + 63) / 64, 256, 0, stream>>>(h, Bcat, ob, beff, out);
}

// Round 3
// 283.771 us; speedup vs baseline: 2.3874x; 1.0628x over previous
//
#include <hip/hip_runtime.h>
#include <stdint.h>

#define B_   16
#define T_   2048
#define D_   1024
#define TT_  2046
#define W_   682            // MAX_WORDS
#define BW_  (B_ * W_)      // 10912
#define NMUT 64
#define NBIN 32

typedef __attribute__((ext_vector_type(8))) short s8b;    // 8 bf16 (4 VGPRs)
typedef __attribute__((ext_vector_type(4))) float f32x4;

__device__ inline short f2bf(float f) {                   // RNE f32->bf16
    uint32_t u = __builtin_bit_cast(uint32_t, f);
    u += 0x7FFFu + ((u >> 16) & 1u);
    return (short)(u >> 16);
}

__device__ inline float fast_tanh(float x) {
    float xc = fminf(fmaxf(x, -15.f), 15.f);
    float e  = __expf(2.f * xc);
    return 1.f - 2.f / (e + 1.f);
}

__device__ inline void gload_lds16(const void* g, void* l) {
    __builtin_amdgcn_global_load_lds(
        (const __attribute__((address_space(1))) uint32_t*)g,
        (__attribute__((address_space(3))) uint32_t*)l, 16, 0, 0);
}

// ---------------------------------------------------------------------------
// K0: merged prep.
//   blocks [0,16)        : word-boundary scan (one block per batch row)
//   blocks [16,1040)     : dense_w fp32->bf16
//   blocks [1040,1104)   : out_w  fp32->bf16 into Bcat rows 0..63
//   blocks [1104,1136)   : W_eff fold -> Bcat rows 64..95 (+ b_eff)
// ---------------------------------------------------------------------------
__global__ __launch_bounds__(256) void k_prep(const int* __restrict__ ws,
                                              const float* __restrict__ dw,
                                              const float* __restrict__ ow,
                                              const float* __restrict__ ob,
                                              const float* __restrict__ bw,
                                              const float* __restrict__ bb,
                                              int* __restrict__ starts,
                                              int* __restrict__ nwords,
                                              short* __restrict__ dwb,
                                              short* __restrict__ Bcat,
                                              float* __restrict__ beff) {
    __shared__ float smem[NMUT];
    int blk = blockIdx.x;
    int tid = threadIdx.x;

    if (blk < 16) {
        // ---- word boundaries via block scan ----
        int b = blk;
        const int* row = ws + (size_t)b * TT_;
        int vals[8], incl[8];
        int p = 0;
        int t0 = tid * 8;
#pragma unroll
        for (int i = 0; i < 8; ++i) {
            int t = t0 + i;
            int v = (t < TT_) ? row[t] : 0;
            vals[i] = v;
            p += v;
            incl[i] = p;
        }
        int tot = p;
        int lane = tid & 63;
        int x = tot;
#pragma unroll
        for (int off = 1; off < 64; off <<= 1) {
            int v = __shfl_up(x, off);
            if (lane >= off) x += v;
        }
        int* wsum = (int*)smem;
        int wid = tid >> 6;
        if (lane == 63) wsum[wid] = x;
        __syncthreads();
        int wbase = 0;
        for (int q = 0; q < wid; ++q) wbase += wsum[q];
        int excl = wbase + x - tot;
        int* st = starts + (size_t)b * (W_ + 1);
#pragma unroll
        for (int i = 0; i < 8; ++i) {
            if (vals[i]) {
                int w = excl + incl[i] - 1;
                if (w <= W_) st[w] = t0 + i;
            }
        }
        if (tid == 0) {
            int total = wsum[0] + wsum[1] + wsum[2] + wsum[3];
            int nw = total < W_ ? total : W_;
            nwords[b] = nw;
            if (total <= W_) st[total] = TT_;
        }
    } else if (blk < 16 + 1024) {
        // ---- dense_w cast ----
        int i = (blk - 16) * 256 + tid;            // n4 = 262144
        float4 v = ((const float4*)dw)[i];
        short4 o;
        o.x = f2bf(v.x); o.y = f2bf(v.y); o.z = f2bf(v.z); o.w = f2bf(v.w);
        *(short4*)(dwb + (size_t)i * 4) = o;
    } else if (blk < 16 + 1024 + 64) {
        // ---- out_w cast into Bcat[0:64] ----
        int i = (blk - 1040) * 256 + tid;          // n4 = 16384
        float4 v = ((const float4*)ow)[i];
        short4 o;
        o.x = f2bf(v.x); o.y = f2bf(v.y); o.z = f2bf(v.z); o.w = f2bf(v.w);
        *(short4*)(Bcat + (size_t)i * 4) = o;
    } else {
        // ---- W_eff fold into Bcat[64:96] ----
        int j = blk - 1104;
        if (tid < NMUT) smem[tid] = bw[(size_t)j * (D_ + NMUT) + tid];
        __syncthreads();
        for (int k = tid; k < D_; k += 256) {
            float acc = bw[(size_t)j * (D_ + NMUT) + NMUT + k];
#pragma unroll 8
            for (int c = 0; c < NMUT; ++c)
                acc = fmaf(smem[c], ow[(size_t)c * D_ + k], acc);
            Bcat[(size_t)(NMUT + j) * D_ + k] = f2bf(acc);
        }
        if (tid == 0) {
            float acc = bb[j];
            for (int c = 0; c < NMUT; ++c) acc = fmaf(smem[c], ob[c], acc);
            beff[j] = acc;
        }
    }
}

// ---------------------------------------------------------------------------
// K2: word feature sums -> bf16. One block per (b, w).
// ---------------------------------------------------------------------------
__global__ __launch_bounds__(256) void k_wf(const float* __restrict__ feat,
                                            const int* __restrict__ starts,
                                            const int* __restrict__ nwords,
                                            short* __restrict__ wf) {
    int blk = blockIdx.x;
    int b = blk / W_;
    int w = blk - b * W_;
    int tid = threadIdx.x;
    short* outp = wf + (size_t)blk * D_ + tid * 4;
    int nw = nwords[b];
    float4 acc = make_float4(0.f, 0.f, 0.f, 0.f);
    if (w >= nw) {
        acc = make_float4(1.f, 1.f, 1.f, 1.f);
    } else {
        const int* st = starts + (size_t)b * (W_ + 1);
        int s = st[w], e = st[w + 1];
        const float4* base = (const float4*)(feat + ((size_t)b * T_ + 1) * D_) + tid;
        for (int t = s; t < e; ++t) {
            float4 v = base[(size_t)t * (D_ / 4)];
            acc.x += v.x; acc.y += v.y; acc.z += v.z; acc.w += v.w;
        }
    }
    short4 o;
    o.x = f2bf(acc.x); o.y = f2bf(acc.y); o.z = f2bf(acc.z); o.w = f2bf(acc.w);
    *(short4*)outp = o;
}

// ---------------------------------------------------------------------------
// K4: h = tanh(wf . dense_w^T + db) via MFMA bf16.
// 128x128 tile, BK=64 as two 32-k sub-buffers (m97 LDS layout preserved,
// half the barrier drains). C/D layout: col=lane&15, row=(lane>>4)*4+reg.
// ---------------------------------------------------------------------------
__global__ __launch_bounds__(256) void k_gemm1(const short* __restrict__ wf,
                                               const short* __restrict__ dwb,
                                               const float* __restrict__ db,
                                               short* __restrict__ h) {
    __shared__ short As[2][128 * 32];
    __shared__ short Bs[2][128 * 32];
    int tid  = threadIdx.x;
    int lane = tid & 63;
    int w    = tid >> 6;
    int wm = w >> 1, wn = w & 1;
    int bm = blockIdx.x * 128;
    int bn = blockIdx.y * 128;

    int ln = lane & 15;
    int qk = lane >> 4;

    int srow = lane >> 2;        // 16 rows per 1KB wave chunk
    int scol = (lane & 3) * 8;   // 4 x 8 bf16 = 32 k per row

    f32x4 acc[4][4];
#pragma unroll
    for (int i = 0; i < 4; ++i)
#pragma unroll
        for (int j = 0; j < 4; ++j) acc[i][j] = (f32x4){0.f, 0.f, 0.f, 0.f};

    for (int kt = 0; kt < D_; kt += 64) {
#pragma unroll
        for (int hh = 0; hh < 2; ++hh) {
#pragma unroll
            for (int p = 0; p < 2; ++p) {
                int chunk = w * 2 + p;               // 0..7, 16 rows each
                int arow = bm + chunk * 16 + srow;
                arow = arow < BW_ ? arow : BW_ - 1;  // clamp tail
                gload_lds16(wf + (size_t)arow * D_ + kt + hh * 32 + scol,
                            &As[hh][chunk * 512]);
                int brow = bn + chunk * 16 + srow;
                gload_lds16(dwb + (size_t)brow * D_ + kt + hh * 32 + scol,
                            &Bs[hh][chunk * 512]);
            }
        }
        __syncthreads();
#pragma unroll
        for (int hh = 0; hh < 2; ++hh) {
            s8b af[4], bf[4];
#pragma unroll
            for (int i = 0; i < 4; ++i)
                af[i] = *(const s8b*)&As[hh][(wm * 64 + i * 16 + ln) * 32 + qk * 8];
#pragma unroll
            for (int j = 0; j < 4; ++j)
                bf[j] = *(const s8b*)&Bs[hh][(wn * 64 + j * 16 + ln) * 32 + qk * 8];
#pragma unroll
            for (int i = 0; i < 4; ++i)
#pragma unroll
                for (int j = 0; j < 4; ++j)
                    acc[i][j] = __builtin_amdgcn_mfma_f32_16x16x32_bf16(
                        af[i], bf[j], acc[i][j], 0, 0, 0);
        }
        __syncthreads();
    }

    float bias[4];
#pragma unroll
    for (int j = 0; j < 4; ++j) bias[j] = db[bn + wn * 64 + j * 16 + ln];
#pragma unroll
    for (int i = 0; i < 4; ++i) {
        int row0 = bm + wm * 64 + i * 16 + qk * 4;
#pragma unroll
        for (int r = 0; r < 4; ++r) {
            int row = row0 + r;
            if (row < BW_) {
#pragma unroll
                for (int j = 0; j < 4; ++j) {
                    int cn = bn + wn * 64 + j * 16 + ln;
                    h[(size_t)row * D_ + cn] =
                        f2bf(fast_tanh(acc[i][j][r] + bias[j]));
                }
            }
        }
    }
}

// ---------------------------------------------------------------------------
// K5: [wcl | bin] = h . Bcat^T + bias via MFMA. Barrier-free: each wave
// loads its A fragments straight from h (L3-resident) in A-operand layout,
// B frags from L2-hot Bcat. 16 rows/wave, 4 waves/block.
// ---------------------------------------------------------------------------
__global__ __launch_bounds__(256) void k_gemm2(const short* __restrict__ h,
                                               const short* __restrict__ Bcat,
                                               const float* __restrict__ ob,
                                               const float* __restrict__ beff,
                                               float* __restrict__ out) {
    int tid  = threadIdx.x;
    int lane = tid & 63;
    int w    = tid >> 6;
    int ln = lane & 15, qk = lane >> 4;
    int m0 = blockIdx.x * 64 + w * 16;

    int arow = m0 + ln;
    arow = arow < BW_ ? arow : BW_ - 1;
    const short* ap = h + (size_t)arow * D_ + qk * 8;
    const short* bp = Bcat + (size_t)ln * D_ + qk * 8;

    f32x4 acc[6];
#pragma unroll
    for (int j = 0; j < 6; ++j) acc[j] = (f32x4){0.f, 0.f, 0.f, 0.f};

#pragma unroll 4
    for (int kt = 0; kt < D_; kt += 32) {
        s8b af = *(const s8b*)(ap + kt);
        s8b bf[6];
#pragma unroll
        for (int j = 0; j < 6; ++j)
            bf[j] = *(const s8b*)(bp + (size_t)j * 16 * D_ + kt);
#pragma unroll
        for (int j = 0; j < 6; ++j)
            acc[j] = __builtin_amdgcn_mfma_f32_16x16x32_bf16(af, bf[j], acc[j], 0, 0, 0);
    }

    float bj[6];
#pragma unroll
    for (int j = 0; j < 6; ++j) {
        int c = j * 16 + ln;
        bj[j] = (c < NMUT) ? ob[c] : beff[c - NMUT];
    }
#pragma unroll
    for (int r = 0; r < 4; ++r) {
        int row = m0 + qk * 4 + r;
        if (row < BW_) {
#pragma unroll
            for (int j = 0; j < 6; ++j) {
                int c = j * 16 + ln;
                float v = acc[j][r] + bj[j];
                if (c < NMUT) out[(size_t)row * NMUT + c] = v;
                else out[(size_t)BW_ * NMUT + (size_t)row * NBIN + (c - NMUT)] = v;
            }
        }
    }
}

// ---------------------------------------------------------------------------
extern "C" void kernel_launch(void* const* d_in, const int* in_sizes, int n_in,
                              void* d_out, int out_size, void* d_ws, size_t ws_size,
                              hipStream_t stream) {
    const float* feat    = (const float*)d_in[0];
    const int*   wstarts = (const int*)d_in[1];
    const float* dw      = (const float*)d_in[2];
    const float* db      = (const float*)d_in[3];
    const float* ow      = (const float*)d_in[4];
    const float* ob      = (const float*)d_in[5];
    const float* bw      = (const float*)d_in[6];
    const float* bb      = (const float*)d_in[7];
    float* out = (float*)d_out;

    char* ws = (char*)d_ws;
    size_t off = 0;
    auto alloc = [&](size_t bytes) {
        void* p = ws + off;
        off += (bytes + 255) & ~(size_t)255;
        return p;
    };
    short* wf     = (short*)alloc((size_t)BW_ * D_ * 2);
    short* h      = (short*)alloc((size_t)BW_ * D_ * 2);
    short* dwb    = (short*)alloc((size_t)D_ * D_ * 2);
    short* Bcat   = (short*)alloc((size_t)(NMUT + NBIN) * D_ * 2);
    float* beff   = (float*)alloc(NBIN * 4);
    int*   starts = (int*)alloc((size_t)B_ * (W_ + 1) * 4);
    int*   nwords = (int*)alloc(B_ * 4);

    k_prep<<<1136, 256, 0, stream>>>(wstarts, dw, ow, ob, bw, bb,
                                     starts, nwords, dwb, Bcat, beff);
    k_wf<<<BW_, 256, 0, stream>>>(feat, starts, nwords, wf);
    k_gemm1<<<dim3((BW_ + 127) / 128, D_ / 128), 256, 0, stream>>>(wf, dwb, db, h);
    k_gemm2<<<(BW_ + 63) / 64, 256, 0, stream>>>(h, Bcat, ob, beff, out);
}